// Round 8
// baseline (381.281 us; speedup 1.0000x reference)
//
#include <hip/hip_runtime.h>
#include <hip/hip_cooperative_groups.h>
#include <hip/hip_bf16.h>
#include <math.h>

namespace cg = cooperative_groups;

#define IN_F 512
#define OUT_F 256
#define ALPHA 0.2f
#define CAP 512     // max row degree; deg ~ Poisson(32)
#define NCHAIN 16   // sub-chains per row for parallel linked-list traversal

typedef __attribute__((ext_vector_type(8))) short bf16x8;
typedef __attribute__((ext_vector_type(8))) unsigned short u16x8;
typedef __attribute__((ext_vector_type(4))) float f32x4;

static __device__ __forceinline__ unsigned short f2bf(float f) {
  unsigned int u = __builtin_bit_cast(unsigned int, f);
  unsigned int r = (u + 0x7FFFu + ((u >> 16) & 1u)) >> 16;  // RNE
  return (unsigned short)r;
}

struct SM {
  union {
    struct { unsigned short lA[64][72]; unsigned short lB[64][72]; } g;  // 18432 B
    struct {
      int tgt[2][CAP];
      float w[2][CAP];
      int len[2][NCHAIN];
      int base[2][NCHAIN + 1];
      float red[2][4];
    } r;                                                                  // 8488 B
  };
};

struct P {
  const float *x, *W, *bias, *a;
  const int* edges;
  unsigned short *xb, *Wb, *hb;
  float *s1, *s2, *hsum;
  int* head;
  int2* rec;
  float* out;
  int N, E, mtiles, gblocks, fblocks;
};

// ================= phase A: convert x,W -> bf16; init head/s1/s2/hsum =================
static __device__ __forceinline__ void phaseA(const P& p, int gtid, int gstride) {
  const int nx4 = p.N * IN_F / 4, nw4 = OUT_F * IN_F / 4;
  const int total4 = nx4 + nw4;
  for (int i4 = gtid; i4 < total4; i4 += gstride) {
    float4 v = (i4 < nx4) ? ((const float4*)p.x)[i4] : ((const float4*)p.W)[i4 - nx4];
    ushort4 o;
    o.x = f2bf(v.x); o.y = f2bf(v.y); o.z = f2bf(v.z); o.w = f2bf(v.w);
    if (i4 < nx4) ((ushort4*)p.xb)[i4] = o;
    else          ((ushort4*)p.Wb)[i4 - nx4] = o;
  }
  const int nh = NCHAIN * p.N;
  for (int i = gtid; i < nh; i += gstride) p.head[i] = -1;
  for (int i = gtid; i < p.N; i += gstride) { p.s1[i] = 0.f; p.s2[i] = 0.f; }
  if (gtid < OUT_F) p.hsum[gtid] = 0.f;
}

// ================= phase B: one virtual block = GEMM tile or edge-fill chunk =================
static __device__ __forceinline__ void phaseB_one(SM& sm, const P& p, int vb) {
  const int tid = threadIdx.x;
  if (vb >= p.gblocks) {
    // ---- edge fill: 16-way per-row linked lists ----
    int idx = (vb - p.gblocks) * 256 + tid;
    if (idx < p.E) {
      int srcv = p.edges[idx];
      int tgtv = p.edges[p.E + idx];
      int c = idx & (NCHAIN - 1);
      int old = atomicExch(&p.head[srcv * NCHAIN + c], idx);
      p.rec[idx] = make_int2(old, tgtv);
    }
    return;
  }
  // ---- GEMM tile ----
  const int bm = (vb % p.mtiles) * 64;
  const int bn = (vb / p.mtiles) * 64;
  const int wave = tid >> 6, lane = tid & 63;
  const int wr = wave >> 1, wc = wave & 1;
  const int lr = lane & 15, lk = lane >> 4;

  f32x4 acc[2][2] = {};

  for (int k0 = 0; k0 < IN_F; k0 += 64) {
#pragma unroll
    for (int r = 0; r < 2; ++r) {
      int idx = tid + r * 256;          // 0..511 -> 64 rows x 8 col-groups
      int row = idx >> 3, c8 = (idx & 7) * 8;
      int gm = bm + row;
      u16x8 va = {0, 0, 0, 0, 0, 0, 0, 0};
      if (gm < p.N) va = *(const u16x8*)&p.xb[(size_t)gm * IN_F + k0 + c8];
      *(u16x8*)&sm.g.lA[row][c8] = va;
      u16x8 vbq = *(const u16x8*)&p.Wb[(size_t)(bn + row) * IN_F + k0 + c8];
      *(u16x8*)&sm.g.lB[row][c8] = vbq;
    }
    __syncthreads();
#pragma unroll
    for (int kk = 0; kk < 64; kk += 32) {
      bf16x8 af[2], bfr[2];
#pragma unroll
      for (int fm = 0; fm < 2; ++fm)
        af[fm] = *(const bf16x8*)&sm.g.lA[wr * 32 + fm * 16 + lr][kk + lk * 8];
#pragma unroll
      for (int fn = 0; fn < 2; ++fn)
        bfr[fn] = *(const bf16x8*)&sm.g.lB[wc * 32 + fn * 16 + lr][kk + lk * 8];
#pragma unroll
      for (int fm = 0; fm < 2; ++fm)
#pragma unroll
        for (int fn = 0; fn < 2; ++fn)
          acc[fm][fn] = __builtin_amdgcn_mfma_f32_16x16x32_bf16(af[fm], bfr[fn],
                                                                acc[fm][fn], 0, 0, 0);
    }
    __syncthreads();
  }

  // fused epilogue. C/D layout: col=lane&15, row=(lane>>4)*4+reg
  int gc[2];
  float av[2], bv[2], biasv[2], csum[2] = {0.f, 0.f};
#pragma unroll
  for (int fn = 0; fn < 2; ++fn) {
    gc[fn] = bn + wc * 32 + fn * 16 + lr;
    av[fn] = p.a[gc[fn]];
    bv[fn] = p.a[OUT_F + gc[fn]];
    biasv[fn] = p.bias[gc[fn]];
  }
#pragma unroll
  for (int fm = 0; fm < 2; ++fm) {
#pragma unroll
    for (int i = 0; i < 4; ++i) {
      int gr = bm + wr * 32 + fm * 16 + lk * 4 + i;
      bool valid = (gr < p.N);
      float v0 = valid ? acc[fm][0][i] + biasv[0] : 0.f;
      float v1 = valid ? acc[fm][1][i] + biasv[1] : 0.f;
      if (valid) {
        p.hb[(size_t)gr * OUT_F + gc[0]] = f2bf(v0);
        p.hb[(size_t)gr * OUT_F + gc[1]] = f2bf(v1);
      }
      csum[0] += v0; csum[1] += v1;
      float p1 = v0 * av[0] + v1 * av[1];
      float p2 = v0 * bv[0] + v1 * bv[1];
#pragma unroll
      for (int off = 1; off < 16; off <<= 1) {
        p1 += __shfl_xor(p1, off);
        p2 += __shfl_xor(p2, off);
      }
      if (lr == 0 && valid) {
        atomicAdd(&p.s1[gr], p1);
        atomicAdd(&p.s2[gr], p2);
      }
    }
  }
#pragma unroll
  for (int off = 16; off < 64; off <<= 1) {
    csum[0] += __shfl_xor(csum[0], off);
    csum[1] += __shfl_xor(csum[1], off);
  }
  if (lk == 0) {
    atomicAdd(&p.hsum[gc[0]], csum[0]);
    atomicAdd(&p.hsum[gc[1]], csum[1]);
  }
}

// ================= phase C: rows r0, r0+1 (two 128-thread halves of a 256 block) =================
static __device__ __forceinline__ void phaseC_pair(SM& sm, const P& p, int r0) {
  const int tid = threadIdx.x;
  const float invN = 1.0f / (float)p.N;
  const int half = tid >> 7;
  const int t = tid & 127;
  const int lane = t & 63, wv = t >> 6;

  int row = r0 + half;
  bool rv = (row < p.N);

  // pass 1: chain lengths
  if (t < NCHAIN) {
    int len = 0;
    if (rv) {
      int e = p.head[row * NCHAIN + t];
      while (e >= 0) { ++len; e = p.rec[e].x; }
    }
    sm.r.len[half][t] = len;
  }
  __syncthreads();
  if (t == 0) {
    int run = 0;
#pragma unroll
    for (int c = 0; c < NCHAIN; ++c) { sm.r.base[half][c] = run; run += sm.r.len[half][c]; }
    sm.r.base[half][NCHAIN] = run;
  }
  __syncthreads();
  int deg = sm.r.base[half][NCHAIN];
  if (deg > CAP) deg = CAP;

  // pass 2: deterministic placement (layout independent of atomic timing)
  if (rv && t < NCHAIN) {
    int e = p.head[row * NCHAIN + t];
    int i = sm.r.base[half][t];
    while (e >= 0) {
      int2 rr = p.rec[e];
      if (i < CAP) sm.r.tgt[half][i] = rr.y;
      ++i;
      e = rr.x;
    }
  }
  __syncthreads();

  // raw leaky scores
  float s1i = rv ? p.s1[row] : 0.f;
  for (int q = t; q < deg; q += 128) {
    int tg = sm.r.tgt[half][q];
    float s = s1i + p.s2[tg];
    sm.r.w[half][q] = (s > 0.f) ? s : ALPHA * s;
  }
  __syncthreads();

  // duplicate merge: leader slot gets cnt*score, others -inf (own-slot writes only)
  for (int q = t; q < deg; q += 128) {
    int tg = sm.r.tgt[half][q];
    int first = q, cnt = 0;
    for (int j = 0; j < deg; ++j) {
      int tj = sm.r.tgt[half][j];
      cnt += (tj == tg);
      if (tj == tg && j < first) first = j;
    }
    float v;
    if (first == q) {
      v = (float)cnt * sm.r.w[half][q];
      if (v == 0.f) v = -INFINITY;  // adj==0 -> NEG_BIG -> excluded
    } else {
      v = -INFINITY;
    }
    sm.r.w[half][q] = v;
  }

  // per-half max
  float m = -INFINITY;
  for (int q = t; q < deg; q += 128) m = fmaxf(m, sm.r.w[half][q]);
#pragma unroll
  for (int off = 32; off; off >>= 1) m = fmaxf(m, __shfl_xor(m, off));
  if (lane == 0) sm.r.red[half][wv] = m;
  __syncthreads();
  m = fmaxf(sm.r.red[half][0], sm.r.red[half][1]);

  bool uniform = (deg == 0) || (m == -INFINITY);

  // exp + denom (skipped when uniform -> avoids -inf - -inf NaN)
  float dsum = 0.f;
  if (!uniform) {
    for (int q = t; q < deg; q += 128) {
      float e = __expf(sm.r.w[half][q] - m);
      sm.r.w[half][q] = e;
      dsum += e;
    }
  }
#pragma unroll
  for (int off = 32; off; off >>= 1) dsum += __shfl_xor(dsum, off);
  if (lane == 0) sm.r.red[half][2 + wv] = dsum;
  __syncthreads();
  float inv = 1.0f / (sm.r.red[half][2] + sm.r.red[half][3]);

  // gather + store (predicated; no barriers inside)
  if (rv) {
    float2* out2 = (float2*)(p.out + (size_t)row * OUT_F);
    if (uniform) {
      out2[t] = make_float2(p.hsum[2 * t] * invN, p.hsum[2 * t + 1] * invN);
    } else {
      const unsigned int* hu = (const unsigned int*)p.hb;
      float L0 = 0.f, L1 = 0.f, L2 = 0.f, L3 = 0.f, L4 = 0.f, L5 = 0.f, L6 = 0.f, L7 = 0.f;
      float H0 = 0.f, H1 = 0.f, H2 = 0.f, H3 = 0.f, H4 = 0.f, H5 = 0.f, H6 = 0.f, H7 = 0.f;
      int q = 0;
      for (; q + 8 <= deg; q += 8) {
        int t0 = sm.r.tgt[half][q],     t1 = sm.r.tgt[half][q + 1];
        int t2 = sm.r.tgt[half][q + 2], t3 = sm.r.tgt[half][q + 3];
        int t4 = sm.r.tgt[half][q + 4], t5 = sm.r.tgt[half][q + 5];
        int t6 = sm.r.tgt[half][q + 6], t7 = sm.r.tgt[half][q + 7];
        float w0 = sm.r.w[half][q],     w1 = sm.r.w[half][q + 1];
        float w2 = sm.r.w[half][q + 2], w3 = sm.r.w[half][q + 3];
        float w4 = sm.r.w[half][q + 4], w5 = sm.r.w[half][q + 5];
        float w6 = sm.r.w[half][q + 6], w7 = sm.r.w[half][q + 7];
        unsigned int u0 = hu[(size_t)t0 * 128 + t], u1 = hu[(size_t)t1 * 128 + t];
        unsigned int u2 = hu[(size_t)t2 * 128 + t], u3 = hu[(size_t)t3 * 128 + t];
        unsigned int u4 = hu[(size_t)t4 * 128 + t], u5 = hu[(size_t)t5 * 128 + t];
        unsigned int u6 = hu[(size_t)t6 * 128 + t], u7 = hu[(size_t)t7 * 128 + t];
        L0 += w0 * __builtin_bit_cast(float, u0 << 16);
        H0 += w0 * __builtin_bit_cast(float, u0 & 0xffff0000u);
        L1 += w1 * __builtin_bit_cast(float, u1 << 16);
        H1 += w1 * __builtin_bit_cast(float, u1 & 0xffff0000u);
        L2 += w2 * __builtin_bit_cast(float, u2 << 16);
        H2 += w2 * __builtin_bit_cast(float, u2 & 0xffff0000u);
        L3 += w3 * __builtin_bit_cast(float, u3 << 16);
        H3 += w3 * __builtin_bit_cast(float, u3 & 0xffff0000u);
        L4 += w4 * __builtin_bit_cast(float, u4 << 16);
        H4 += w4 * __builtin_bit_cast(float, u4 & 0xffff0000u);
        L5 += w5 * __builtin_bit_cast(float, u5 << 16);
        H5 += w5 * __builtin_bit_cast(float, u5 & 0xffff0000u);
        L6 += w6 * __builtin_bit_cast(float, u6 << 16);
        H6 += w6 * __builtin_bit_cast(float, u6 & 0xffff0000u);
        L7 += w7 * __builtin_bit_cast(float, u7 << 16);
        H7 += w7 * __builtin_bit_cast(float, u7 & 0xffff0000u);
      }
      for (; q < deg; ++q) {
        float w = sm.r.w[half][q];
        unsigned int u = hu[(size_t)sm.r.tgt[half][q] * 128 + t];
        L0 += w * __builtin_bit_cast(float, u << 16);
        H0 += w * __builtin_bit_cast(float, u & 0xffff0000u);
      }
      float accL = ((L0 + L1) + (L2 + L3)) + ((L4 + L5) + (L6 + L7));
      float accH = ((H0 + H1) + (H2 + H3)) + ((H4 + H5) + (H6 + H7));
      out2[t] = make_float2(accL * inv, accH * inv);
    }
  }
  __syncthreads();  // protect LDS reuse by caller's next iteration
}

// ================= cooperative single-kernel path =================
__global__ __launch_bounds__(256, 4) void fused_all(P p) {
  __shared__ SM sm;
  const int gstride = gridDim.x * 256;
  const int gtid = blockIdx.x * 256 + threadIdx.x;

  phaseA(p, gtid, gstride);
  __threadfence();
  cg::this_grid().sync();

  const int total = p.gblocks + p.fblocks;
  for (int vb = blockIdx.x; vb < total; vb += gridDim.x) phaseB_one(sm, p, vb);
  __threadfence();
  cg::this_grid().sync();

  for (int r0 = blockIdx.x * 2; r0 < p.N; r0 += gridDim.x * 2) phaseC_pair(sm, p, r0);
}

// ================= fallback 3-kernel path =================
__global__ __launch_bounds__(256) void k_prep(P p) {
  phaseA(p, blockIdx.x * 256 + threadIdx.x, gridDim.x * 256);
}
__global__ __launch_bounds__(256) void k_mega(P p) {
  __shared__ SM sm;
  phaseB_one(sm, p, blockIdx.x);
}
__global__ __launch_bounds__(256) void k_row(P p) {
  __shared__ SM sm;
  phaseC_pair(sm, p, blockIdx.x * 2);
}

extern "C" void kernel_launch(void* const* d_in, const int* in_sizes, int n_in,
                              void* d_out, int out_size, void* d_ws, size_t ws_size,
                              hipStream_t stream) {
  P p;
  p.x = (const float*)d_in[0];
  p.W = (const float*)d_in[1];
  p.bias = (const float*)d_in[2];
  p.a = (const float*)d_in[3];
  p.edges = (const int*)d_in[4];
  p.out = (float*)d_out;

  p.N = in_sizes[0] / IN_F;   // 10000
  p.E = in_sizes[4] / 2;      // 320000

  char* ws = (char*)d_ws;
  size_t off = 0;
  auto alloc = [&](size_t bytes) {
    char* q = ws + off;
    off = (off + bytes + 255) & ~(size_t)255;
    return q;
  };
  p.hb   = (unsigned short*)alloc((size_t)p.N * OUT_F * sizeof(unsigned short));
  p.xb   = (unsigned short*)alloc((size_t)p.N * IN_F * sizeof(unsigned short));
  p.Wb   = (unsigned short*)alloc((size_t)OUT_F * IN_F * sizeof(unsigned short));
  p.s1   = (float*)alloc((size_t)p.N * sizeof(float));
  p.s2   = (float*)alloc((size_t)p.N * sizeof(float));
  p.hsum = (float*)alloc(OUT_F * sizeof(float));
  p.head = (int*)alloc((size_t)NCHAIN * p.N * sizeof(int));
  p.rec  = (int2*)alloc((size_t)p.E * sizeof(int2));

  p.mtiles = (p.N + 63) / 64;
  p.gblocks = p.mtiles * (OUT_F / 64);
  p.fblocks = (p.E + 255) / 256;

  // ---- try cooperative single-kernel; fall back to 3 dispatches on any failure ----
  bool coop_ok = false;
  int nblk = 0;
  hipError_t qerr = hipOccupancyMaxActiveBlocksPerMultiprocessor(&nblk, fused_all, 256, 0);
  if (qerr == hipSuccess && nblk > 0) {
    int grid = nblk * 256;           // 256 CUs on MI355X; all phases are grid-strided
    if (grid > 2048) grid = 2048;
    void* args[] = {(void*)&p};
    hipError_t lerr = hipLaunchCooperativeKernel((void*)fused_all, dim3(grid), dim3(256),
                                                 args, 0, stream);
    coop_ok = (lerr == hipSuccess);
  }
  if (!coop_ok) {
    (void)hipGetLastError();  // clear sticky error from the failed coop launch
    k_prep<<<1024, 256, 0, stream>>>(p);
    k_mega<<<p.gblocks + p.fblocks, 256, 0, stream>>>(p);
    k_row<<<(p.N + 1) / 2, 256, 0, stream>>>(p);
  }
}

// Round 9
// 75.080 us; speedup vs baseline: 5.0784x; 5.0784x over previous
//
#include <hip/hip_runtime.h>
#include <hip/hip_bf16.h>
#include <math.h>

#define IN_F 512
#define OUT_F 256
#define ALPHA 0.2f
#define CAP 512     // max row degree; deg ~ Poisson(32)
#define NCHAIN 16   // sub-chains per row for parallel linked-list traversal

typedef __attribute__((ext_vector_type(8))) short bf16x8;
typedef __attribute__((ext_vector_type(4))) float f32x4;

static __device__ __forceinline__ unsigned short f2bf(float f) {
  unsigned int u = __builtin_bit_cast(unsigned int, f);
  unsigned int r = (u + 0x7FFFu + ((u >> 16) & 1u)) >> 16;  // RNE
  return (unsigned short)r;
}

// ================= mega: [0,gblocks) = GEMM(+epilogue partials), rest = edge fill =================
// GEMM reads fp32 x/W directly, converts to bf16 during LDS staging (no prep pass).
// Epilogue writes bf16 h, plus DIRECT-WRITE partials (no atomics, no zero-init needed):
//   s1p[row*4+bn4], s2p[row*4+bn4]  (per-n-block partial dots with attention vector)
//   hsump[mtile*256+col]            (per-m-tile column sums, for the empty-row fallback)
__global__ __launch_bounds__(256) void mega(const float* __restrict__ x,
                                            const float* __restrict__ W,
                                            const float* __restrict__ bias,
                                            const float* __restrict__ a,
                                            const int* __restrict__ edges,
                                            unsigned short* __restrict__ hb,
                                            float* __restrict__ s1p,
                                            float* __restrict__ s2p,
                                            float* __restrict__ hsump,
                                            int* __restrict__ head,
                                            int2* __restrict__ rec,
                                            int N_, int E_, int mtiles, int gblocks) {
  const int tid = threadIdx.x;
  const int vb = blockIdx.x;

  if (vb >= gblocks) {
    // ---- edge fill: 16-way per-row linked lists. No head init needed: any negative
    // value (0xAA poison, or -1 left by rowk) terminates a chain.
    int idx = (vb - gblocks) * 256 + tid;
    if (idx < E_) {
      int srcv = edges[idx];
      int tgtv = edges[E_ + idx];
      int old = atomicExch(&head[srcv * NCHAIN + (idx & (NCHAIN - 1))], idx);
      rec[idx] = make_int2(old, tgtv);
    }
    return;
  }

  // ---- GEMM tile 64x64, BK=64 ----
  __shared__ unsigned short lA[64][72];  // pad 72: rows 8 apart alias banks 2-way (free)
  __shared__ unsigned short lB[64][72];
  __shared__ float s1t[64], s2t[64], ht[64];

  const int bm = (vb % mtiles) * 64;
  const int bn4 = vb / mtiles;          // 0..3
  const int bn = bn4 * 64;
  const int wave = tid >> 6, lane = tid & 63;
  const int wr = wave >> 1, wc = wave & 1;
  const int lr = lane & 15, lk = lane >> 4;

  f32x4 acc[2][2] = {};

  for (int k0 = 0; k0 < IN_F; k0 += 64) {
#pragma unroll
    for (int r = 0; r < 4; ++r) {
      int idx = tid + r * 256;          // 0..1023 -> 64 rows x 16 float4-groups
      int row = idx >> 4, c4 = idx & 15;
      int gm = bm + row;
      float4 va = (gm < N_) ? *(const float4*)&x[(size_t)gm * IN_F + k0 + c4 * 4]
                            : make_float4(0.f, 0.f, 0.f, 0.f);
      ushort4 oa;
      oa.x = f2bf(va.x); oa.y = f2bf(va.y); oa.z = f2bf(va.z); oa.w = f2bf(va.w);
      *(ushort4*)&lA[row][c4 * 4] = oa;
      float4 vbq = *(const float4*)&W[(size_t)(bn + row) * IN_F + k0 + c4 * 4];
      ushort4 ob;
      ob.x = f2bf(vbq.x); ob.y = f2bf(vbq.y); ob.z = f2bf(vbq.z); ob.w = f2bf(vbq.w);
      *(ushort4*)&lB[row][c4 * 4] = ob;
    }
    __syncthreads();
#pragma unroll
    for (int kk = 0; kk < 64; kk += 32) {
      bf16x8 af[2], bfr[2];
#pragma unroll
      for (int fm = 0; fm < 2; ++fm)
        af[fm] = *(const bf16x8*)&lA[wr * 32 + fm * 16 + lr][kk + lk * 8];
#pragma unroll
      for (int fn = 0; fn < 2; ++fn)
        bfr[fn] = *(const bf16x8*)&lB[wc * 32 + fn * 16 + lr][kk + lk * 8];
#pragma unroll
      for (int fm = 0; fm < 2; ++fm)
#pragma unroll
        for (int fn = 0; fn < 2; ++fn)
          acc[fm][fn] = __builtin_amdgcn_mfma_f32_16x16x32_bf16(af[fm], bfr[fn],
                                                                acc[fm][fn], 0, 0, 0);
    }
    __syncthreads();
  }

  // ---- epilogue. C/D layout: col=lane&15, row=(lane>>4)*4+reg ----
  if (tid < 64) { s1t[tid] = 0.f; s2t[tid] = 0.f; ht[tid] = 0.f; }
  __syncthreads();

  int gc[2];
  float av[2], bv[2], biasv[2], csum[2] = {0.f, 0.f};
#pragma unroll
  for (int fn = 0; fn < 2; ++fn) {
    gc[fn] = bn + wc * 32 + fn * 16 + lr;
    av[fn] = a[gc[fn]];
    bv[fn] = a[OUT_F + gc[fn]];
    biasv[fn] = bias[gc[fn]];
  }
#pragma unroll
  for (int fm = 0; fm < 2; ++fm) {
#pragma unroll
    for (int i = 0; i < 4; ++i) {
      int lrow = wr * 32 + fm * 16 + lk * 4 + i;
      int gr = bm + lrow;
      bool valid = (gr < N_);
      float v0 = valid ? acc[fm][0][i] + biasv[0] : 0.f;
      float v1 = valid ? acc[fm][1][i] + biasv[1] : 0.f;
      if (valid) {
        hb[(size_t)gr * OUT_F + gc[0]] = f2bf(v0);
        hb[(size_t)gr * OUT_F + gc[1]] = f2bf(v1);
      }
      csum[0] += v0; csum[1] += v1;
      // partial dot over this block's 64 cols; cols live across the 16-lane lr-group
      float p1 = v0 * av[0] + v1 * av[1];
      float p2 = v0 * bv[0] + v1 * bv[1];
#pragma unroll
      for (int off = 1; off < 16; off <<= 1) {
        p1 += __shfl_xor(p1, off);
        p2 += __shfl_xor(p2, off);
      }
      if (lr == 0) {               // 2 contributors per lrow (wc=0,1) -> LDS combine
        atomicAdd(&s1t[lrow], p1);
        atomicAdd(&s2t[lrow], p2);
      }
    }
  }
  // col sums: rows live across lk-groups (xor 16,32); 2 contributors (wr=0,1)
#pragma unroll
  for (int off = 16; off < 64; off <<= 1) {
    csum[0] += __shfl_xor(csum[0], off);
    csum[1] += __shfl_xor(csum[1], off);
  }
  if (lk == 0) {
    atomicAdd(&ht[wc * 32 + 0 * 16 + lr], csum[0]);
    atomicAdd(&ht[wc * 32 + 1 * 16 + lr], csum[1]);
  }
  __syncthreads();

  if (tid < 64) {
    int gr = bm + tid;
    if (gr < N_) {
      s1p[(size_t)gr * 4 + bn4] = s1t[tid];
      s2p[(size_t)gr * 4 + bn4] = s2t[tid];
    }
    hsump[(size_t)(bm >> 6) * OUT_F + bn + tid] = ht[tid];
  }
}

// ================= rowk: traverse chains, merge dups, softmax, gather; leave head=-1 =================
__global__ __launch_bounds__(256) void rowk(const unsigned short* __restrict__ hb,
                                            const float* __restrict__ s1p,
                                            const float* __restrict__ s2p,
                                            const float* __restrict__ hsump,
                                            int* __restrict__ head,
                                            const int2* __restrict__ rec,
                                            float* __restrict__ out,
                                            int N_, int E_, int mtiles) {
  __shared__ int s_tgt[2][CAP];
  __shared__ float s_w[2][CAP];
  __shared__ int s_len[2][NCHAIN];
  __shared__ int s_base[2][NCHAIN + 1];
  __shared__ float s_red[2][4];

  const int tid = threadIdx.x;
  const float invN = 1.0f / (float)N_;
  const int half = tid >> 7;        // 0/1 -> two rows per block
  const int t = tid & 127;
  const int lane = t & 63, wv = t >> 6;

  int row = blockIdx.x * 2 + half;
  bool rv = (row < N_);

  // pass 1: chain lengths (bounded, negative-terminated)
  if (t < NCHAIN) {
    int len = 0;
    if (rv) {
      int e = head[row * NCHAIN + t];
      while (e >= 0 && e < E_ && len < CAP) { ++len; e = rec[e].x; }
    }
    s_len[half][t] = len;
  }
  __syncthreads();
  if (t == 0) {
    int run = 0;
#pragma unroll
    for (int c = 0; c < NCHAIN; ++c) { s_base[half][c] = run; run += s_len[half][c]; }
    s_base[half][NCHAIN] = run;
  }
  __syncthreads();
  int deg = s_base[half][NCHAIN];
  if (deg > CAP) deg = CAP;

  // pass 2: deterministic placement + leave-clean head reset (own slot only)
  if (rv && t < NCHAIN) {
    int e = head[row * NCHAIN + t];
    int i = s_base[half][t];
    int cnt = 0;
    while (e >= 0 && e < E_ && cnt < CAP) {
      int2 rr = rec[e];
      if (i < CAP) s_tgt[half][i] = rr.y;
      ++i; ++cnt;
      e = rr.x;
    }
    head[row * NCHAIN + t] = -1;   // next call starts with clean chains
  }
  __syncthreads();

  // raw leaky scores; s1/s2 = sum of the 4 per-n-block partials (one float4 each)
  float s1i = 0.f;
  if (rv) {
    float4 sv = *(const float4*)&s1p[(size_t)row * 4];
    s1i = (sv.x + sv.y) + (sv.z + sv.w);
  }
  for (int q = t; q < deg; q += 128) {
    int tg = s_tgt[half][q];
    float4 s2v = *(const float4*)&s2p[(size_t)tg * 4];
    float s = s1i + ((s2v.x + s2v.y) + (s2v.z + s2v.w));
    s_w[half][q] = (s > 0.f) ? s : ALPHA * s;
  }
  __syncthreads();

  // duplicate merge: leader slot gets cnt*score, others -inf (own-slot writes only)
  for (int q = t; q < deg; q += 128) {
    int tg = s_tgt[half][q];
    int first = q, cnt = 0;
    for (int j = 0; j < deg; ++j) {
      int tj = s_tgt[half][j];
      cnt += (tj == tg);
      if (tj == tg && j < first) first = j;
    }
    float v;
    if (first == q) {
      v = (float)cnt * s_w[half][q];
      if (v == 0.f) v = -INFINITY;  // adj==0 -> NEG_BIG -> excluded
    } else {
      v = -INFINITY;
    }
    s_w[half][q] = v;
  }

  // per-half max
  float m = -INFINITY;
  for (int q = t; q < deg; q += 128) m = fmaxf(m, s_w[half][q]);
#pragma unroll
  for (int off = 32; off; off >>= 1) m = fmaxf(m, __shfl_xor(m, off));
  if (lane == 0) s_red[half][wv] = m;
  __syncthreads();
  m = fmaxf(s_red[half][0], s_red[half][1]);

  bool uniform = (deg == 0) || (m == -INFINITY);

  // exp + denom (skipped when uniform -> avoids -inf - -inf NaN)
  float dsum = 0.f;
  if (!uniform) {
    for (int q = t; q < deg; q += 128) {
      float e = __expf(s_w[half][q] - m);
      s_w[half][q] = e;
      dsum += e;
    }
  }
#pragma unroll
  for (int off = 32; off; off >>= 1) dsum += __shfl_xor(dsum, off);
  if (lane == 0) s_red[half][2 + wv] = dsum;
  __syncthreads();
  float inv = 1.0f / (s_red[half][2] + s_red[half][3]);

  if (rv) {
    float2* out2 = (float2*)(out + (size_t)row * OUT_F);
    if (uniform) {
      // empty row -> softmax of constant row -> mean of h (on-demand column sum)
      float A = 0.f, B = 0.f;
      for (int mt = 0; mt < mtiles; ++mt) {
        A += hsump[(size_t)mt * OUT_F + 2 * t];
        B += hsump[(size_t)mt * OUT_F + 2 * t + 1];
      }
      out2[t] = make_float2(A * invN, B * invN);
    } else {
      // branch-free gather: uint = 2 bf16 per thread, 8 edges in flight
      const unsigned int* hu = (const unsigned int*)hb;
      float L0 = 0.f, L1 = 0.f, L2 = 0.f, L3 = 0.f, L4 = 0.f, L5 = 0.f, L6 = 0.f, L7 = 0.f;
      float H0 = 0.f, H1 = 0.f, H2 = 0.f, H3 = 0.f, H4 = 0.f, H5 = 0.f, H6 = 0.f, H7 = 0.f;
      int q = 0;
      for (; q + 8 <= deg; q += 8) {
        int t0 = s_tgt[half][q],     t1 = s_tgt[half][q + 1];
        int t2 = s_tgt[half][q + 2], t3 = s_tgt[half][q + 3];
        int t4 = s_tgt[half][q + 4], t5 = s_tgt[half][q + 5];
        int t6 = s_tgt[half][q + 6], t7 = s_tgt[half][q + 7];
        float w0 = s_w[half][q],     w1 = s_w[half][q + 1];
        float w2 = s_w[half][q + 2], w3 = s_w[half][q + 3];
        float w4 = s_w[half][q + 4], w5 = s_w[half][q + 5];
        float w6 = s_w[half][q + 6], w7 = s_w[half][q + 7];
        unsigned int u0 = hu[(size_t)t0 * 128 + t], u1 = hu[(size_t)t1 * 128 + t];
        unsigned int u2 = hu[(size_t)t2 * 128 + t], u3 = hu[(size_t)t3 * 128 + t];
        unsigned int u4 = hu[(size_t)t4 * 128 + t], u5 = hu[(size_t)t5 * 128 + t];
        unsigned int u6 = hu[(size_t)t6 * 128 + t], u7 = hu[(size_t)t7 * 128 + t];
        L0 += w0 * __builtin_bit_cast(float, u0 << 16);
        H0 += w0 * __builtin_bit_cast(float, u0 & 0xffff0000u);
        L1 += w1 * __builtin_bit_cast(float, u1 << 16);
        H1 += w1 * __builtin_bit_cast(float, u1 & 0xffff0000u);
        L2 += w2 * __builtin_bit_cast(float, u2 << 16);
        H2 += w2 * __builtin_bit_cast(float, u2 & 0xffff0000u);
        L3 += w3 * __builtin_bit_cast(float, u3 << 16);
        H3 += w3 * __builtin_bit_cast(float, u3 & 0xffff0000u);
        L4 += w4 * __builtin_bit_cast(float, u4 << 16);
        H4 += w4 * __builtin_bit_cast(float, u4 & 0xffff0000u);
        L5 += w5 * __builtin_bit_cast(float, u5 << 16);
        H5 += w5 * __builtin_bit_cast(float, u5 & 0xffff0000u);
        L6 += w6 * __builtin_bit_cast(float, u6 << 16);
        H6 += w6 * __builtin_bit_cast(float, u6 & 0xffff0000u);
        L7 += w7 * __builtin_bit_cast(float, u7 << 16);
        H7 += w7 * __builtin_bit_cast(float, u7 & 0xffff0000u);
      }
      for (; q < deg; ++q) {
        float w = s_w[half][q];
        unsigned int u = hu[(size_t)s_tgt[half][q] * 128 + t];
        L0 += w * __builtin_bit_cast(float, u << 16);
        H0 += w * __builtin_bit_cast(float, u & 0xffff0000u);
      }
      float accL = ((L0 + L1) + (L2 + L3)) + ((L4 + L5) + (L6 + L7));
      float accH = ((H0 + H1) + (H2 + H3)) + ((H4 + H5) + (H6 + H7));
      out2[t] = make_float2(accL * inv, accH * inv);
    }
  }
}

extern "C" void kernel_launch(void* const* d_in, const int* in_sizes, int n_in,
                              void* d_out, int out_size, void* d_ws, size_t ws_size,
                              hipStream_t stream) {
  const float* x = (const float*)d_in[0];
  const float* W = (const float*)d_in[1];
  const float* b = (const float*)d_in[2];
  const float* a = (const float*)d_in[3];
  const int* edges = (const int*)d_in[4];
  float* out = (float*)d_out;

  int N_ = in_sizes[0] / IN_F;   // 10000
  int E_ = in_sizes[4] / 2;      // 320000

  char* ws = (char*)d_ws;
  size_t off = 0;
  auto alloc = [&](size_t bytes) {
    char* q = ws + off;
    off = (off + bytes + 255) & ~(size_t)255;
    return q;
  };
  int mtiles = (N_ + 63) / 64;
  unsigned short* hb    = (unsigned short*)alloc((size_t)N_ * OUT_F * sizeof(unsigned short));
  float*          s1p   = (float*)alloc((size_t)N_ * 4 * sizeof(float));
  float*          s2p   = (float*)alloc((size_t)N_ * 4 * sizeof(float));
  float*          hsump = (float*)alloc((size_t)mtiles * OUT_F * sizeof(float));
  int*            head  = (int*)alloc((size_t)NCHAIN * N_ * sizeof(int));
  int2*           rec   = (int2*)alloc((size_t)E_ * sizeof(int2));

  int gblocks = mtiles * (OUT_F / 64);
  int fblocks = (E_ + 255) / 256;

  mega<<<gblocks + fblocks, 256, 0, stream>>>(x, W, b, a, edges, hb, s1p, s2p, hsump,
                                              head, rec, N_, E_, mtiles, gblocks);
  rowk<<<(N_ + 1) / 2, 256, 0, stream>>>(hb, s1p, s2p, hsump, head, rec, out, N_, E_, mtiles);
}